// Round 2
// baseline (81.106 us; speedup 1.0000x reference)
//
#include <hip/hip_runtime.h>
#include <math.h>

#define CIN   128
#define COUT  128
#define NMAPS (CIN*COUT)
#define PPC   8128          /* COUT*(COUT-1)/2 pairs per channel */
#define MSTR  24            /* doubles per map: [0..5]=9 floats(+pad), [6..14]=mu, [15..23]=s1 */

__device__ inline unsigned f2key(float f) {
    unsigned b = __float_as_uint(f);
    return (b & 0x80000000u) ? ~b : (b | 0x80000000u);
}
__device__ inline float key2f(unsigned k) {
    unsigned b = (k & 0x80000000u) ? (k ^ 0x80000000u) : ~k;
    return __uint_as_float(b);
}

// reflect-pad 3x3 gaussian blur as separable linear map A·X·A^T,
// A = [[g1,2g0,0],[g0,g1,g0],[0,2g0,g1]]  (double precision)
__device__ inline void blur3d(const double* X, double* O, double g0, double g1) {
    double h0 = 2.0 * g0;
    double T[9];
#pragma unroll
    for (int c = 0; c < 3; ++c) {
        double x0 = X[c], x1 = X[3 + c], x2 = X[6 + c];
        T[c]     = g1 * x0 + h0 * x1;
        T[3 + c] = g0 * (x0 + x2) + g1 * x1;
        T[6 + c] = h0 * x1 + g1 * x2;
    }
#pragma unroll
    for (int r = 0; r < 3; ++r) {
        double t0 = T[3 * r], t1 = T[3 * r + 1], t2 = T[3 * r + 2];
        O[3 * r]     = g1 * t0 + h0 * t1;
        O[3 * r + 1] = g0 * (t0 + t2) + g1 * t1;
        O[3 * r + 2] = h0 * t1 + g1 * t2;
    }
}

__global__ __launch_bounds__(256) void k_init(unsigned* mmx, float* segsum, float* segcnt) {
    int t = threadIdx.x;
    if (t == 0) { mmx[0] = 0xFFFFFFFFu; mmx[1] = 0u; }
    if (t < 128) segsum[t] = 0.0f;
    else         segcnt[t - 128] = 0.0f;
}

// Per-map precompute (fp64): mu=blur(x), s1=blur(x*x)-mu^2 ; plus global min/max.
__global__ __launch_bounds__(256) void k_pre(const float* __restrict__ in,
                                             double* __restrict__ pre,
                                             unsigned* __restrict__ mmx,
                                             double g0, double g1) {
    int m = blockIdx.x * 256 + threadIdx.x;   // grid exactly covers NMAPS
    float lmin = 1e30f, lmax = -1e30f;
    float xf[9];
    double x[9];
#pragma unroll
    for (int k = 0; k < 9; ++k) {
        xf[k] = in[m * 9 + k];
        lmin = fminf(lmin, xf[k]);
        lmax = fmaxf(lmax, xf[k]);
        x[k] = (double)xf[k];
    }
    double mu[9];
    blur3d(x, mu, g0, g1);
    double xx[9];
#pragma unroll
    for (int k = 0; k < 9; ++k) xx[k] = x[k] * x[k];
    double bxx[9];
    blur3d(xx, bxx, g0, g1);

    double* p = pre + (size_t)m * MSTR;
    float*  pf = (float*)p;
#pragma unroll
    for (int k = 0; k < 9; ++k) pf[k] = xf[k];
#pragma unroll
    for (int k = 0; k < 9; ++k) {
        p[6 + k]  = mu[k];
        p[15 + k] = bxx[k] - mu[k] * mu[k];
    }
#pragma unroll
    for (int o = 32; o > 0; o >>= 1) {
        lmin = fminf(lmin, __shfl_down(lmin, o));
        lmax = fmaxf(lmax, __shfl_down(lmax, o));
    }
    if ((threadIdx.x & 63) == 0) {
        atomicMin(&mmx[0], f2key(lmin));
        atomicMax(&mmx[1], f2key(lmax));
    }
}

// 4 blocks per channel; channel's 128 maps staged in LDS (24.5 KB).
// Accumulate into the reference's MIXED segments: s = (p*128 + c) / 8128.
__global__ __launch_bounds__(256) void k_pairs(const double* __restrict__ pre,
                                               const unsigned* __restrict__ mmx,
                                               float* __restrict__ segsum,
                                               float* __restrict__ segcnt,
                                               double g0, double g1) {
    __shared__ double lds[COUT * MSTR];   // 24576 B
    __shared__ float lsum[128], lcnt[128];
    int c = blockIdx.x >> 2;
    int q = blockIdx.x & 3;

    if (threadIdx.x < 128) { lsum[threadIdx.x] = 0.0f; lcnt[threadIdx.x] = 0.0f; }

    const float4* src = reinterpret_cast<const float4*>(pre + (size_t)c * COUT * MSTR);
    float4* dst = reinterpret_cast<float4*>(lds);
    for (int t = threadIdx.x; t < COUT * MSTR / 2; t += 256) dst[t] = src[t];
    __syncthreads();

    double rng = (double)key2f(mmx[1]) - (double)key2f(mmx[0]);
    if (rng == 0.0) rng = 1.0;
    double C1 = (0.01 * rng) * (0.01 * rng);
    double C2 = (0.03 * rng) * (0.03 * rng);

    for (int p = threadIdx.x + 256 * q; p < PPC; p += 1024) {
        // decode triu pair p -> (a,b), a<b
        int a = (int)((255.0f - sqrtf((float)(65025 - 8 * p))) * 0.5f);
        while ((a + 1) * (255 - (a + 1)) / 2 <= p) ++a;
        while (a * (255 - a) / 2 > p) --a;
        int b = a + 1 + (p - a * (255 - a) / 2);

        const double* Pa = lds + a * MSTR;
        const double* Pb = lds + b * MSTR;
        const float*  xa = (const float*)Pa;
        const float*  xb = (const float*)Pb;

        double z[9];
#pragma unroll
        for (int k = 0; k < 9; ++k) z[k] = (double)xa[k] * (double)xb[k];
        double bz[9];
        blur3d(z, bz, g0, g1);

        double ssum = 0.0;
#pragma unroll
        for (int k = 0; k < 9; ++k) {
            double ma = Pa[6 + k], mb = Pb[6 + k];
            double mu12 = ma * mb;
            double s12  = bz[k] - mu12;
            double num  = (2.0 * mu12 + C1) * (2.0 * s12 + C2);
            double den  = (ma * ma + mb * mb + C1) * (Pa[15 + k] + Pb[15 + k] + C2);
            ssum += num / den;
        }
        double hg = ssum / 9.0 - 0.9;
        if (hg > 0.0) {
            unsigned seg = (unsigned)(p * 128 + c) / 8128u;
            atomicAdd(&lsum[seg], (float)hg);
            atomicAdd(&lcnt[seg], 1.0f);
        }
    }
    __syncthreads();
    if (threadIdx.x < 128) {
        float s = lsum[threadIdx.x], n = lcnt[threadIdx.x];
        if (s != 0.0f || n != 0.0f) {
            atomicAdd(&segsum[threadIdx.x], s);
            atomicAdd(&segcnt[threadIdx.x], n);
        }
    }
}

__global__ __launch_bounds__(128) void k_fin(const float* __restrict__ segsum,
                                             const float* __restrict__ segcnt,
                                             float* __restrict__ out) {
    int t = threadIdx.x;   // 0..127
    double v = (double)segsum[t] / fmax((double)segcnt[t], 1.0);
#pragma unroll
    for (int o = 32; o > 0; o >>= 1) v += __shfl_down(v, o);
    __shared__ double ws2[2];
    if ((t & 63) == 0) ws2[t >> 6] = v;
    __syncthreads();
    if (t == 0) out[0] = (float)((ws2[0] + ws2[1]) * (1.0 / 128.0));
}

extern "C" void kernel_launch(void* const* d_in, const int* in_sizes, int n_in,
                              void* d_out, int out_size, void* d_ws, size_t ws_size,
                              hipStream_t stream) {
    const float* in = (const float*)d_in[0];
    float* out = (float*)d_out;
    char* ws = (char*)d_ws;

    unsigned* mmx = (unsigned*)ws;                 // 8 B
    float* segsum = (float*)(ws + 256);            // 512 B
    float* segcnt = (float*)(ws + 768);            // 512 B
    double* pre   = (double*)(ws + 2048);          // NMAPS*MSTR*8 = 3 MB

    // gaussian(3, sigma=1.5) weights in double (matches np float64 reference)
    double e = exp(-1.0 / 4.5);
    double s = 2.0 * e + 1.0;
    double g0 = e / s;
    double g1 = 1.0 / s;

    k_init <<<1, 256, 0, stream>>>(mmx, segsum, segcnt);
    k_pre  <<<NMAPS / 256, 256, 0, stream>>>(in, pre, mmx, g0, g1);
    k_pairs<<<CIN * 4, 256, 0, stream>>>(pre, mmx, segsum, segcnt, g0, g1);
    k_fin  <<<1, 128, 0, stream>>>(segsum, segcnt, out);
}

// Round 3
// 78.791 us; speedup vs baseline: 1.0294x; 1.0294x over previous
//
#include <hip/hip_runtime.h>
#include <math.h>

#define CIN   128
#define COUT  128
#define NMAPS (CIN*COUT)
#define PPC   8128          /* COUT*(COUT-1)/2 */
#define F32S  27            /* floats per map: x[9], mu[9], s1[9] */
#define F64S  24            /* doubles per map: x as 9 floats in [0..5], mu [6..14], s1 [15..23] */
#define LCAP  (1u<<21)      /* 2M entries > total pairs: overflow impossible */
#define BPC   8             /* k_pairs blocks per channel */

// ---------------- helpers ----------------

__device__ inline void decode_pair(int p, int& a, int& b) {
    int a0 = (int)((255.0f - sqrtf((float)(65025 - 8 * p))) * 0.5f);
    if (a0 < 0) a0 = 0;
    if (a0 > 126) a0 = 126;
    while ((a0 + 1) * (255 - (a0 + 1)) / 2 <= p) ++a0;
    while (a0 * (255 - a0) / 2 > p) --a0;
    a = a0;
    b = a0 + 1 + (p - a0 * (255 - a0) / 2);
}

// reflect-pad 3x3 gaussian blur = A·X·A^T, A = [[g1,2g0,0],[g0,g1,g0],[0,2g0,g1]]
__device__ inline void blur3f(const float* X, float* O, float g0, float g1) {
    float h0 = 2.0f * g0;
    float T[9];
#pragma unroll
    for (int c = 0; c < 3; ++c) {
        float x0 = X[c], x1 = X[3 + c], x2 = X[6 + c];
        T[c]     = g1 * x0 + h0 * x1;
        T[3 + c] = g0 * (x0 + x2) + g1 * x1;
        T[6 + c] = h0 * x1 + g1 * x2;
    }
#pragma unroll
    for (int r = 0; r < 3; ++r) {
        float t0 = T[3 * r], t1 = T[3 * r + 1], t2 = T[3 * r + 2];
        O[3 * r]     = g1 * t0 + h0 * t1;
        O[3 * r + 1] = g0 * (t0 + t2) + g1 * t1;
        O[3 * r + 2] = h0 * t1 + g1 * t2;
    }
}

__device__ inline void blur3d(const double* X, double* O, double g0, double g1) {
    double h0 = 2.0 * g0;
    double T[9];
#pragma unroll
    for (int c = 0; c < 3; ++c) {
        double x0 = X[c], x1 = X[3 + c], x2 = X[6 + c];
        T[c]     = g1 * x0 + h0 * x1;
        T[3 + c] = g0 * (x0 + x2) + g1 * x1;
        T[6 + c] = h0 * x1 + g1 * x2;
    }
#pragma unroll
    for (int r = 0; r < 3; ++r) {
        double t0 = T[3 * r], t1 = T[3 * r + 1], t2 = T[3 * r + 2];
        O[3 * r]     = g1 * t0 + h0 * t1;
        O[3 * r + 1] = g0 * (t0 + t2) + g1 * t1;
        O[3 * r + 2] = h0 * t1 + g1 * t2;
    }
}

// ---------------- kernel 1: per-map precompute (f32 + f64 packs), min/max, zeroing ----------------

__global__ __launch_bounds__(256) void k_pre(const float* __restrict__ in,
                                             float* __restrict__ pre32,
                                             double* __restrict__ pre64,
                                             float* __restrict__ pbmin,
                                             float* __restrict__ pbmax,
                                             float* __restrict__ segsum,
                                             float* __restrict__ segcnt,
                                             unsigned* __restrict__ listc,
                                             float g0f, float g1f,
                                             double g0, double g1) {
    __shared__ float stg[2304];            // 256 maps * 9
    int tid = threadIdx.x;
    int base = blockIdx.x * 2304;
    for (int i = tid; i < 2304; i += 256) stg[i] = in[base + i];   // coalesced
    __syncthreads();

    float xf[9];
    float lmin = 1e30f, lmax = -1e30f;
#pragma unroll
    for (int k = 0; k < 9; ++k) {
        xf[k] = stg[tid * 9 + k];          // stride 9 (odd) -> conflict-free
        lmin = fminf(lmin, xf[k]);
        lmax = fmaxf(lmax, xf[k]);
    }
    int m = blockIdx.x * 256 + tid;

    // f32 pack (screening)
    {
        float mu[9], q[9], bq[9];
        blur3f(xf, mu, g0f, g1f);
#pragma unroll
        for (int k = 0; k < 9; ++k) q[k] = xf[k] * xf[k];
        blur3f(q, bq, g0f, g1f);
        float* o = pre32 + m * F32S;
#pragma unroll
        for (int k = 0; k < 9; ++k) {
            o[k]      = xf[k];
            o[9 + k]  = mu[k];
            o[18 + k] = bq[k] - mu[k] * mu[k];
        }
    }
    // f64 pack (exact path)
    {
        double xd[9], mud[9], qd[9], bqd[9];
#pragma unroll
        for (int k = 0; k < 9; ++k) xd[k] = (double)xf[k];
        blur3d(xd, mud, g0, g1);
#pragma unroll
        for (int k = 0; k < 9; ++k) qd[k] = xd[k] * xd[k];
        blur3d(qd, bqd, g0, g1);
        double* od = pre64 + (size_t)m * F64S;
        float* odf = (float*)od;
#pragma unroll
        for (int k = 0; k < 9; ++k) odf[k] = xf[k];
#pragma unroll
        for (int k = 0; k < 9; ++k) {
            od[6 + k]  = mud[k];
            od[15 + k] = bqd[k] - mud[k] * mud[k];
        }
    }

    // block min/max -> per-block arrays (no init, no atomics)
#pragma unroll
    for (int o = 32; o > 0; o >>= 1) {
        lmin = fminf(lmin, __shfl_down(lmin, o));
        lmax = fmaxf(lmax, __shfl_down(lmax, o));
    }
    __shared__ float rmn[4], rmx[4];
    if ((tid & 63) == 0) { rmn[tid >> 6] = lmin; rmx[tid >> 6] = lmax; }
    __syncthreads();
    if (tid == 0) {
        pbmin[blockIdx.x] = fminf(fminf(rmn[0], rmn[1]), fminf(rmn[2], rmn[3]));
        pbmax[blockIdx.x] = fmaxf(fmaxf(rmx[0], rmx[1]), fmaxf(rmx[2], rmx[3]));
    }
    if (blockIdx.x == 0) {
        if (tid < 128) { segsum[tid] = 0.0f; segcnt[tid] = 0.0f; }
        if (tid == 128) *listc = 0u;
    }
}

// ---------------- kernel 2: fp32 screening over all pairs ----------------

__global__ __launch_bounds__(256) void k_pairs(const float* __restrict__ pre32,
                                               const float* __restrict__ pbmin,
                                               const float* __restrict__ pbmax,
                                               unsigned* __restrict__ listc,
                                               unsigned* __restrict__ list,
                                               double* __restrict__ c12,
                                               float g0f, float g1f) {
    __shared__ float P[COUT * F32S];       // 13824 B, stride 27 (odd -> conflict-free)
    __shared__ float cc[2];
    int tid = threadIdx.x;
    int c = blockIdx.x >> 3, q = blockIdx.x & 7;

    const float* src = pre32 + (size_t)c * COUT * F32S;
    for (int i = tid; i < COUT * F32S; i += 256) P[i] = src[i];   // coalesced

    if (tid < 64) {
        float mn = pbmin[tid], mx = pbmax[tid];
#pragma unroll
        for (int o = 32; o > 0; o >>= 1) {
            mn = fminf(mn, __shfl_down(mn, o));
            mx = fmaxf(mx, __shfl_down(mx, o));
        }
        if (tid == 0) {
            double rng = (double)mx - (double)mn;
            if (rng == 0.0) rng = 1.0;
            double C1 = (0.01 * rng) * (0.01 * rng);
            double C2 = (0.03 * rng) * (0.03 * rng);
            cc[0] = (float)C1; cc[1] = (float)C2;
            if (blockIdx.x == 0) { c12[0] = C1; c12[1] = C2; }
        }
    }
    __syncthreads();
    float C1 = cc[0], C2 = cc[1];

#pragma unroll
    for (int it = 0; it < 4; ++it) {
        int p = it * 2048 + q * 256 + tid;
        if (p >= PPC) break;               // only last iteration of q==7 tail
        int a, b;
        decode_pair(p, a, b);
        const float* A = P + a * F32S;     // wave-mostly-uniform a -> broadcast reads
        const float* B = P + b * F32S;     // consecutive b -> conflict-free

        float z[9], bz[9];
#pragma unroll
        for (int k = 0; k < 9; ++k) z[k] = A[k] * B[k];
        blur3f(z, bz, g0f, g1f);

        // sum of 9 fractions as one fused fraction: 1 divide per pair
        float an = 0.0f, ad = 1.0f;
#pragma unroll
        for (int k = 0; k < 9; ++k) {
            float ma = A[9 + k], mb = B[9 + k];
            float mu12 = ma * mb;
            float s12  = bz[k] - mu12;
            float nn = fmaf(2.0f, mu12, C1) * fmaf(2.0f, s12, C2);
            float dd = fmaf(ma, ma, fmaf(mb, mb, C1)) * (A[18 + k] + B[18 + k] + C2);
            an = an * dd + nn * ad;
            ad *= dd;
        }
        float ssim = an / (ad * 9.0f);
        if (ssim > 0.897f) {               // screen with 3e-3 margin (f32 err ~1e-5)
            unsigned idx = atomicAdd(listc, 1u);
            if (idx < LCAP) list[idx] = (unsigned)((c << 13) | p);
        }
    }
}

// ---------------- kernel 3: exact fp64 recompute of screened-in pairs ----------------

__global__ __launch_bounds__(256) void k_fb(const double* __restrict__ pre64,
                                            const unsigned* __restrict__ listc,
                                            const unsigned* __restrict__ list,
                                            const double* __restrict__ c12,
                                            float* __restrict__ segsum,
                                            float* __restrict__ segcnt,
                                            double g0, double g1) {
    unsigned n = *listc;
    if (n > LCAP) n = LCAP;
    double C1 = c12[0], C2 = c12[1];
    for (unsigned i = blockIdx.x * 256 + threadIdx.x; i < n; i += gridDim.x * 256) {
        unsigned u = list[i];
        int c = (int)(u >> 13), p = (int)(u & 8191);
        int a, b;
        decode_pair(p, a, b);
        const double* Pa = pre64 + ((size_t)c * COUT + a) * F64S;
        const double* Pb = pre64 + ((size_t)c * COUT + b) * F64S;
        const float* xa = (const float*)Pa;
        const float* xb = (const float*)Pb;

        double z[9], bz[9];
#pragma unroll
        for (int k = 0; k < 9; ++k) z[k] = (double)xa[k] * (double)xb[k];
        blur3d(z, bz, g0, g1);

        double ssum = 0.0;
#pragma unroll
        for (int k = 0; k < 9; ++k) {
            double ma = Pa[6 + k], mb = Pb[6 + k];
            double mu12 = ma * mb;
            double s12  = bz[k] - mu12;
            double num  = (2.0 * mu12 + C1) * (2.0 * s12 + C2);
            double den  = (ma * ma + mb * mb + C1) * (Pa[15 + k] + Pb[15 + k] + C2);
            ssum += num / den;
        }
        double hg = ssum / 9.0 - 0.9;
        if (hg > 0.0) {
            unsigned seg = (unsigned)(p * 128 + c) / 8128u;   // reference's mixed segments
            atomicAdd(&segsum[seg], (float)hg);
            atomicAdd(&segcnt[seg], 1.0f);
        }
    }
}

// ---------------- kernel 4: final reduce ----------------

__global__ __launch_bounds__(128) void k_fin(const float* __restrict__ segsum,
                                             const float* __restrict__ segcnt,
                                             float* __restrict__ out) {
    int t = threadIdx.x;
    double v = (double)segsum[t] / fmax((double)segcnt[t], 1.0);
#pragma unroll
    for (int o = 32; o > 0; o >>= 1) v += __shfl_down(v, o);
    __shared__ double ws2[2];
    if ((t & 63) == 0) ws2[t >> 6] = v;
    __syncthreads();
    if (t == 0) out[0] = (float)((ws2[0] + ws2[1]) * (1.0 / 128.0));
}

// ---------------- launch ----------------

extern "C" void kernel_launch(void* const* d_in, const int* in_sizes, int n_in,
                              void* d_out, int out_size, void* d_ws, size_t ws_size,
                              hipStream_t stream) {
    const float* in = (const float*)d_in[0];
    float* out = (float*)d_out;
    char* ws = (char*)d_ws;

    float*    pbmin  = (float*)(ws + 0);
    float*    pbmax  = (float*)(ws + 256);
    float*    segsum = (float*)(ws + 512);
    float*    segcnt = (float*)(ws + 1024);
    unsigned* listc  = (unsigned*)(ws + 1536);
    double*   c12    = (double*)(ws + 1544);
    float*    pre32  = (float*)(ws + 2048);                    // 16384*27*4 = 1769472 B
    double*   pre64  = (double*)(ws + 2048 + 1769472);         // 16384*24*8 = 3145728 B
    unsigned* list   = (unsigned*)(ws + 2048 + 1769472 + 3145728); // 8 MB

    double e = exp(-1.0 / 4.5);
    double s = 2.0 * e + 1.0;
    double g0 = e / s, g1 = 1.0 / s;
    float g0f = (float)g0, g1f = (float)g1;

    k_pre  <<<NMAPS / 256, 256, 0, stream>>>(in, pre32, pre64, pbmin, pbmax,
                                             segsum, segcnt, listc, g0f, g1f, g0, g1);
    k_pairs<<<CIN * BPC, 256, 0, stream>>>(pre32, pbmin, pbmax, listc, list, c12, g0f, g1f);
    k_fb   <<<128, 256, 0, stream>>>(pre64, listc, list, c12, segsum, segcnt, g0, g1);
    k_fin  <<<1, 128, 0, stream>>>(segsum, segcnt, out);
}